// Round 1
// baseline (2294.476 us; speedup 1.0000x reference)
//
#include <hip/hip_runtime.h>

#define S 2048
#define D 64
#define BH 32
#define R 8           // q rows per block
#define SCALE 0.125f  // 1/sqrt(64)

// Detect mask storage: int32 0/1 (words all <=1) vs packed bytes (some word >1).
__global__ void mask_detect_kernel(const unsigned int* __restrict__ m, int* __restrict__ flag) {
    __shared__ int any;
    if (threadIdx.x == 0) any = 0;
    __syncthreads();
    unsigned int v0 = m[threadIdx.x];
    unsigned int v1 = m[threadIdx.x + 256];
    unsigned int v2 = m[threadIdx.x + 512];
    unsigned int v3 = m[threadIdx.x + 768];
    if (v0 > 1u || v1 > 1u || v2 > 1u || v3 > 1u) any = 1;
    __syncthreads();
    if (threadIdx.x == 0) *flag = any;  // 1 => byte mask, 0 => int32 mask
}

__global__ __launch_bounds__(256, 2)
void attn_fused_kernel(const float* __restrict__ q, const float* __restrict__ k,
                       const float* __restrict__ v,
                       const int* __restrict__ mask_i, const unsigned char* __restrict__ mask_b,
                       const int* __restrict__ flag,
                       float* __restrict__ out, float* __restrict__ atten) {
    __shared__ float p_lds[R][S];     // 64 KB: unnormalized exp(scores)
    __shared__ float qs[R][D];        // 2 KB
    __shared__ float red[R][4];
    __shared__ float linv_s[R];
    __shared__ float ored[R][D];      // 2 KB: jhalf=1 PV partials

    const int t  = threadIdx.x;
    const int bh = blockIdx.y;          // 0..31
    const int r0 = blockIdx.x * R;      // q-row base
    const int bz = bh >> 4;             // batch index (H=16)

    // ---- load Q rows (8x64 = 512 floats) ----
    {
        const float* qb = q + (size_t)(bh * S + r0) * D;
        ((float*)qs)[t]       = qb[t];
        ((float*)qs)[t + 256] = qb[t + 256];
    }
    const int bytemode = *flag;
    __syncthreads();

    // ---- Phase A: scores = QK^T * scale, mask, exp (no max-sub: |s| << 88) ----
    const float* kb = k + (size_t)bh * S * D;
    float acc[8][R];   // [j-batch][row]
#pragma unroll
    for (int b8 = 0; b8 < 8; ++b8)
#pragma unroll
        for (int r = 0; r < R; ++r) acc[b8][r] = 0.f;

#pragma unroll 4
    for (int d4 = 0; d4 < 16; ++d4) {
        float4 qv[R];
#pragma unroll
        for (int r = 0; r < R; ++r) qv[r] = *(const float4*)&qs[r][d4 * 4];
#pragma unroll
        for (int b8 = 0; b8 < 8; ++b8) {
            const int j = b8 * 256 + t;
            const float4 kv = *(const float4*)&kb[(size_t)j * D + d4 * 4];
#pragma unroll
            for (int r = 0; r < R; ++r) {
                acc[b8][r] += qv[r].x * kv.x + qv[r].y * kv.y + qv[r].z * kv.z + qv[r].w * kv.w;
            }
        }
    }

    float lsum[R];
#pragma unroll
    for (int r = 0; r < R; ++r) lsum[r] = 0.f;

    const size_t mbase = (size_t)bz * S * S;
#pragma unroll
    for (int b8 = 0; b8 < 8; ++b8) {
        const int j = b8 * 256 + t;
#pragma unroll
        for (int r = 0; r < R; ++r) {
            const size_t midx = mbase + (size_t)(r0 + r) * S + j;
            const int mval = bytemode ? (int)mask_b[midx] : mask_i[midx];
            const float p = mval ? 0.f : __expf(acc[b8][r] * SCALE);
            p_lds[r][j] = p;
            lsum[r] += p;
        }
    }

    // ---- row-sum reduction (64-lane shuffle, then across 4 waves) ----
#pragma unroll
    for (int r = 0; r < R; ++r) {
        float s = lsum[r];
        s += __shfl_down(s, 32);
        s += __shfl_down(s, 16);
        s += __shfl_down(s, 8);
        s += __shfl_down(s, 4);
        s += __shfl_down(s, 2);
        s += __shfl_down(s, 1);
        if ((t & 63) == 0) red[r][t >> 6] = s;
    }
    __syncthreads();
    if (t < R) {
        linv_s[t] = 1.f / (red[t][0] + red[t][1] + red[t][2] + red[t][3]);
    }
    __syncthreads();

    // ---- write atten = p * (1/l), coalesced ----
    {
        float* ab = atten + (size_t)bh * S * S + (size_t)r0 * S;
#pragma unroll
        for (int r = 0; r < R; ++r) {
            const float il = linv_s[r];
#pragma unroll
            for (int b8 = 0; b8 < 8; ++b8) {
                const int j = b8 * 256 + t;
                ab[(size_t)r * S + j] = p_lds[r][j] * il;
            }
        }
    }

    // ---- Phase B: out = (P V) * (1/l) ----
    // thread map: d0 = 4*(t&15), r = (t>>4)&7, jh = t>>7
    const int d0 = (t & 15) * 4;
    const int rr = (t >> 4) & 7;
    const int jh = t >> 7;
    const float* vb = v + (size_t)bh * S * D;
    float4 o = make_float4(0.f, 0.f, 0.f, 0.f);
    const int jbeg = jh * 1024;
    for (int j4 = jbeg; j4 < jbeg + 1024; j4 += 4) {
        const float4 p4 = *(const float4*)&p_lds[rr][j4];
        const float4 va = *(const float4*)&vb[(size_t)(j4 + 0) * D + d0];
        const float4 vb1 = *(const float4*)&vb[(size_t)(j4 + 1) * D + d0];
        const float4 vc = *(const float4*)&vb[(size_t)(j4 + 2) * D + d0];
        const float4 vd = *(const float4*)&vb[(size_t)(j4 + 3) * D + d0];
        o.x += p4.x * va.x + p4.y * vb1.x + p4.z * vc.x + p4.w * vd.x;
        o.y += p4.x * va.y + p4.y * vb1.y + p4.z * vc.y + p4.w * vd.y;
        o.z += p4.x * va.z + p4.y * vb1.z + p4.z * vc.z + p4.w * vd.z;
        o.w += p4.x * va.w + p4.y * vb1.w + p4.z * vc.w + p4.w * vd.w;
    }
    if (jh == 1) {
        *(float4*)&ored[rr][d0] = o;
    }
    __syncthreads();
    if (jh == 0) {
        const float4 o1 = *(const float4*)&ored[rr][d0];
        const float il = linv_s[rr];
        float4 res;
        res.x = (o.x + o1.x) * il;
        res.y = (o.y + o1.y) * il;
        res.z = (o.z + o1.z) * il;
        res.w = (o.w + o1.w) * il;
        *(float4*)&out[(size_t)(bh * S + r0 + rr) * D + d0] = res;
    }
}

extern "C" void kernel_launch(void* const* d_in, const int* in_sizes, int n_in,
                              void* d_out, int out_size, void* d_ws, size_t ws_size,
                              hipStream_t stream) {
    const float* q = (const float*)d_in[0];
    const float* k = (const float*)d_in[1];
    const float* v = (const float*)d_in[2];
    const void* mask = d_in[3];
    float* out   = (float*)d_out;
    float* atten = out + (size_t)BH * S * D;   // outputs concatenated: out, atten
    int* flag = (int*)d_ws;

    mask_detect_kernel<<<1, 256, 0, stream>>>((const unsigned int*)mask, flag);

    dim3 grid(S / R, BH);
    attn_fused_kernel<<<grid, 256, 0, stream>>>(
        q, k, v, (const int*)mask, (const unsigned char*)mask, flag, out, atten);
}

// Round 2
// 860.611 us; speedup vs baseline: 2.6661x; 2.6661x over previous
//
#include <hip/hip_runtime.h>

#define S 2048
#define D 64
#define BH 32
#define CHUNK 128
#define NCH (S / CHUNK)
#define MTILE 64

typedef __attribute__((ext_vector_type(8))) short bfrag;
typedef __attribute__((ext_vector_type(4))) float f32x4;

__device__ __forceinline__ unsigned short f2bf(float f) {
    unsigned int u = __builtin_bit_cast(unsigned int, f);
    u += 0x7fffu + ((u >> 16) & 1u);
    return (unsigned short)(u >> 16);
}
__device__ __forceinline__ ushort4 f2bf4(float4 f) {
    ushort4 u;
    u.x = f2bf(f.x); u.y = f2bf(f.y); u.z = f2bf(f.z); u.w = f2bf(f.w);
    return u;
}

// Detect mask storage: int32 0/1 (first 1024 words all <=1) vs packed bytes.
__global__ void mask_detect_kernel(const unsigned int* __restrict__ m, int* __restrict__ flag) {
    __shared__ int any;
    if (threadIdx.x == 0) any = 0;
    __syncthreads();
    unsigned int v0 = m[threadIdx.x];
    unsigned int v1 = m[threadIdx.x + 256];
    unsigned int v2 = m[threadIdx.x + 512];
    unsigned int v3 = m[threadIdx.x + 768];
    if (v0 > 1u || v1 > 1u || v2 > 1u || v3 > 1u) any = 1;
    __syncthreads();
    if (threadIdx.x == 0) *flag = any;  // 1 => byte mask, 0 => int32 mask
}

__global__ __launch_bounds__(256, 2)
void attn_mfma_kernel(const float* __restrict__ q, const float* __restrict__ k,
                      const float* __restrict__ v,
                      const int* __restrict__ mask_i, const unsigned char* __restrict__ mask_b,
                      const int* __restrict__ flag,
                      float* __restrict__ out, float* __restrict__ atten) {
    // Pads chosen so each +1 row shifts 4 banks (conflict-free b128 frag reads).
    __shared__ __attribute__((aligned(16))) unsigned short Qs[MTILE][72];   //  9216 B
    __shared__ __attribute__((aligned(16))) unsigned short Ks[CHUNK][72];   // 18432 B
    __shared__ __attribute__((aligned(16))) unsigned short Vt[D][136];      // 17408 B (V transposed)
    __shared__ __attribute__((aligned(16))) unsigned short Ps[4][16][136];  // 17408 B (wave-private P)
    __shared__ __attribute__((aligned(16))) unsigned char  Ms[MTILE][132];  //  8448 B

    const int t    = threadIdx.x;
    const int lane = t & 63;
    const int wv   = t >> 6;        // wave 0..3, owns q-rows wv*16..+15
    const int quad = lane >> 4;     // 0..3
    const int l16  = lane & 15;
    const int bh   = blockIdx.y;    // 0..31
    const int r0   = blockIdx.x * MTILE;
    const int bz   = bh >> 4;       // batch (H=16)

    const float* kb = k + (size_t)bh * S * D;
    const float* vb = v + (size_t)bh * S * D;
    const unsigned char* mb = mask_b + (size_t)bz * S * S;
    const int*           mi = mask_i + (size_t)bz * S * S;

    // ---- stage Q, pre-scaled by 1/sqrt(64) ----
    {
        const float* qb = q + ((size_t)bh * S + r0) * D;
        const int r = t >> 2, c0 = (t & 3) * 16;
#pragma unroll
        for (int i = 0; i < 4; ++i) {
            float4 f = *(const float4*)&qb[r * 64 + c0 + i * 4];
            f.x *= 0.125f; f.y *= 0.125f; f.z *= 0.125f; f.w *= 0.125f;
            *(ushort4*)&Qs[r][c0 + i * 4] = f2bf4(f);
        }
    }
    const int bytemode = *flag;

    float lsum[4] = {0.f, 0.f, 0.f, 0.f};
    f32x4 acc_o[4];
#pragma unroll
    for (int n = 0; n < 4; ++n) acc_o[n] = (f32x4){0.f, 0.f, 0.f, 0.f};

    // =================== Phase A: row sums + O = P·V ===================
    for (int ch = 0; ch < NCH; ++ch) {
        const int j0 = ch * CHUNK;
        __syncthreads();  // previous chunk fully consumed (also covers Q staging)
        {   // stage K (row-major bf16) and V (transposed bf16)
            const int r = t >> 1, c0 = (t & 1) * 32;
            const float* sk = &kb[(size_t)(j0 + r) * D + c0];
            const float* sv = &vb[(size_t)(j0 + r) * D + c0];
#pragma unroll
            for (int i = 0; i < 8; ++i) {
                float4 f = *(const float4*)&sk[i * 4];
                *(ushort4*)&Ks[r][c0 + i * 4] = f2bf4(f);
            }
#pragma unroll
            for (int i = 0; i < 8; ++i) {
                float4 f = *(const float4*)&sv[i * 4];
                Vt[c0 + i * 4 + 0][r] = f2bf(f.x);
                Vt[c0 + i * 4 + 1][r] = f2bf(f.y);
                Vt[c0 + i * 4 + 2][r] = f2bf(f.z);
                Vt[c0 + i * 4 + 3][r] = f2bf(f.w);
            }
            // stage mask chunk as bytes
            const int r2 = t >> 2, cb = (t & 3) * 32;
            if (bytemode) {
                const unsigned char* sm = &mb[(size_t)(r0 + r2) * S + j0 + cb];
#pragma unroll
                for (int i = 0; i < 8; ++i)
                    *(unsigned int*)&Ms[r2][cb + i * 4] = *(const unsigned int*)&sm[i * 4];
            } else {
                const int* sm = &mi[(size_t)(r0 + r2) * S + j0 + cb];
#pragma unroll
                for (int i = 0; i < 8; ++i) {
                    int4 w = *(const int4*)&sm[i * 4];
                    unsigned int packed = (unsigned int)(w.x & 1) | ((unsigned int)(w.y & 1) << 8) |
                                          ((unsigned int)(w.z & 1) << 16) | ((unsigned int)(w.w & 1) << 24);
                    *(unsigned int*)&Ms[r2][cb + i * 4] = packed;
                }
            }
        }
        __syncthreads();

        // S = Q·K^T  (scale already folded into Q)
        f32x4 sacc[8];
#pragma unroll
        for (int nt = 0; nt < 8; ++nt) sacc[nt] = (f32x4){0.f, 0.f, 0.f, 0.f};
#pragma unroll
        for (int ks = 0; ks < 2; ++ks) {
            bfrag aq = *(const bfrag*)&Qs[wv * 16 + l16][ks * 32 + quad * 8];
#pragma unroll
            for (int nt = 0; nt < 8; ++nt) {
                bfrag bk = *(const bfrag*)&Ks[nt * 16 + l16][ks * 32 + quad * 8];
                sacc[nt] = __builtin_amdgcn_mfma_f32_16x16x32_bf16(aq, bk, sacc[nt], 0, 0, 0);
            }
        }
        // exp + mask, accumulate row sums, store P (bf16) wave-private
#pragma unroll
        for (int nt = 0; nt < 8; ++nt) {
#pragma unroll
            for (int rg = 0; rg < 4; ++rg) {
                const int rloc = quad * 4 + rg;        // 0..15 within wave
                const int cloc = nt * 16 + l16;        // 0..127 within chunk
                const float p = Ms[wv * 16 + rloc][cloc] ? 0.f : __expf(sacc[nt][rg]);
                lsum[rg] += p;
                Ps[wv][rloc][cloc] = f2bf(p);
            }
        }
        // O += P·V   (Ps is wave-private: in-wave lgkm ordering suffices)
#pragma unroll
        for (int ks = 0; ks < 4; ++ks) {
            bfrag ap = *(const bfrag*)&Ps[wv][l16][ks * 32 + quad * 8];
#pragma unroll
            for (int nt = 0; nt < 4; ++nt) {
                bfrag bv2 = *(const bfrag*)&Vt[nt * 16 + l16][ks * 32 + quad * 8];
                acc_o[nt] = __builtin_amdgcn_mfma_f32_16x16x32_bf16(ap, bv2, acc_o[nt], 0, 0, 0);
            }
        }
    }

    // ---- finish row sums: reduce across the 16 column-lanes ----
    float linv[4];
#pragma unroll
    for (int rg = 0; rg < 4; ++rg) {
        float s2 = lsum[rg];
        s2 += __shfl_xor(s2, 1);
        s2 += __shfl_xor(s2, 2);
        s2 += __shfl_xor(s2, 4);
        s2 += __shfl_xor(s2, 8);
        linv[rg] = 1.f / s2;
    }

    // ---- write O = acc_o / l ----
#pragma unroll
    for (int nt = 0; nt < 4; ++nt) {
#pragma unroll
        for (int rg = 0; rg < 4; ++rg) {
            const int row = r0 + wv * 16 + quad * 4 + rg;
            out[((size_t)bh * S + row) * D + nt * 16 + l16] = acc_o[nt][rg] * linv[rg];
        }
    }

    // =================== Phase B: recompute S, write atten = P/l ===================
    for (int ch = 0; ch < NCH; ++ch) {
        const int j0 = ch * CHUNK;
        __syncthreads();
        {   // stage K + mask only
            const int r = t >> 1, c0 = (t & 1) * 32;
            const float* sk = &kb[(size_t)(j0 + r) * D + c0];
#pragma unroll
            for (int i = 0; i < 8; ++i) {
                float4 f = *(const float4*)&sk[i * 4];
                *(ushort4*)&Ks[r][c0 + i * 4] = f2bf4(f);
            }
            const int r2 = t >> 2, cb = (t & 3) * 32;
            if (bytemode) {
                const unsigned char* sm = &mb[(size_t)(r0 + r2) * S + j0 + cb];
#pragma unroll
                for (int i = 0; i < 8; ++i)
                    *(unsigned int*)&Ms[r2][cb + i * 4] = *(const unsigned int*)&sm[i * 4];
            } else {
                const int* sm = &mi[(size_t)(r0 + r2) * S + j0 + cb];
#pragma unroll
                for (int i = 0; i < 8; ++i) {
                    int4 w = *(const int4*)&sm[i * 4];
                    unsigned int packed = (unsigned int)(w.x & 1) | ((unsigned int)(w.y & 1) << 8) |
                                          ((unsigned int)(w.z & 1) << 16) | ((unsigned int)(w.w & 1) << 24);
                    *(unsigned int*)&Ms[r2][cb + i * 4] = packed;
                }
            }
        }
        __syncthreads();

        f32x4 sacc[8];
#pragma unroll
        for (int nt = 0; nt < 8; ++nt) sacc[nt] = (f32x4){0.f, 0.f, 0.f, 0.f};
#pragma unroll
        for (int ks = 0; ks < 2; ++ks) {
            bfrag aq = *(const bfrag*)&Qs[wv * 16 + l16][ks * 32 + quad * 8];
#pragma unroll
            for (int nt = 0; nt < 8; ++nt) {
                bfrag bk = *(const bfrag*)&Ks[nt * 16 + l16][ks * 32 + quad * 8];
                sacc[nt] = __builtin_amdgcn_mfma_f32_16x16x32_bf16(aq, bk, sacc[nt], 0, 0, 0);
            }
        }
#pragma unroll
        for (int nt = 0; nt < 8; ++nt) {
#pragma unroll
            for (int rg = 0; rg < 4; ++rg) {
                const int rloc = quad * 4 + rg;
                const int cloc = nt * 16 + l16;
                const int rblk = wv * 16 + rloc;
                const float val = Ms[rblk][cloc] ? 0.f : __expf(sacc[nt][rg]) * linv[rg];
                atten[((size_t)bh * S + r0 + rblk) * S + j0 + cloc] = val;
            }
        }
    }
}

extern "C" void kernel_launch(void* const* d_in, const int* in_sizes, int n_in,
                              void* d_out, int out_size, void* d_ws, size_t ws_size,
                              hipStream_t stream) {
    const float* q = (const float*)d_in[0];
    const float* k = (const float*)d_in[1];
    const float* v = (const float*)d_in[2];
    const void* mask = d_in[3];
    float* out   = (float*)d_out;
    float* atten = out + (size_t)BH * S * D;  // outputs concatenated: out, atten
    int* flag = (int*)d_ws;

    mask_detect_kernel<<<1, 256, 0, stream>>>((const unsigned int*)mask, flag);

    dim3 grid(S / MTILE, BH);
    attn_mfma_kernel<<<grid, 256, 0, stream>>>(
        q, k, v, (const int*)mask, (const unsigned char*)mask, flag, out, atten);
}